// Round 3
// baseline (105.557 us; speedup 1.0000x reference)
//
#include <hip/hip_runtime.h>

// ChamferLoss: x,y [4, 8192, 3] fp32 -> scalar fp32.
// out = (sum_bn min_m d2 + sum_bm min_n d2) / 32768
//
// Round 6: counters showed chamfer=44.8us of 98us total (VALUBusy 64%,
// SGPR=96 at cap, HBM 1.3%). Inner loop is AT its VALU floor (~25us);
// remaining losses = 36% in-kernel stall (SMEM lgkmcnt(0) convoy) and
// ~53us of prep/sum/launch overhead. Single-kernel design:
//  * blocks self-stage raw->packed records in LDS (repack + w=|p|^2 at
//    stage time), sweep via wave-uniform ds_read_b64 broadcast
//    (conflict-free, fine-grained lgkmcnt, frees SGPRs).
//  * per-seg partial mins -> ws (plain stores, no init); last seg-block of
//    each 512-query group finalizes (counter + device fences); last group
//    writes *out. prep_kernel and sum_kernel eliminated; only a 520B
//    memset node remains ahead of the main kernel.
// Round 7 (this round): infra failed again; audit found an LDS indexing
// bug in the unverified round-6 source (wave*512 float4s instead of
// wave*256 -> waves 4-7 read past recs4). Fixed; resubmitting.
// Predicted: total 98 -> ~60us; chamfer 44.8 -> ~38-41, VALUBusy -> ~80%.

#define N_      8192
#define NGRP    128           // (dir,batch,qg) groups of 512 queries
#define FLT_BIG 3.0e38f

typedef float v2f __attribute__((ext_vector_type(2)));

__global__ void zero_out_kernel(float* out) { *out = 0.0f; }

// one packed record (2 opposite points, VGPR pairs) vs 4 query-pairs
// pxs={p0x,p1x} pys={p0y,p1y} pzs={p0z,p1z} wv={w0,w1}; q pre-scaled by -2.
static __device__ __forceinline__ void do_record_v(
    v2f pxs, v2f pys, v2f pzs, v2f wv,
    const v2f* qx, const v2f* qy, const v2f* qz,
    float* acc)
{
    #pragma unroll
    for (int j = 0; j < 4; ++j) {
        v2f td, ts;
        // td = {q0*p0, q1*p1} chain; ts = {q0*p1, q1*p0} via op_sel swap
        asm("v_pk_fma_f32 %0, %1, %2, %3"
            : "=v"(td) : "v"(qz[j]), "v"(pzs), "v"(wv));
        asm("v_pk_fma_f32 %0, %1, %2, %3 op_sel:[0,1,1] op_sel_hi:[1,0,0]"
            : "=v"(ts) : "v"(qz[j]), "v"(pzs), "v"(wv));
        asm("v_pk_fma_f32 %0, %1, %2, %0"
            : "+v"(td) : "v"(qy[j]), "v"(pys));
        asm("v_pk_fma_f32 %0, %1, %2, %0 op_sel:[0,1,0] op_sel_hi:[1,0,1]"
            : "+v"(ts) : "v"(qy[j]), "v"(pys));
        asm("v_pk_fma_f32 %0, %1, %2, %0"
            : "+v"(td) : "v"(qx[j]), "v"(pxs));
        asm("v_pk_fma_f32 %0, %1, %2, %0 op_sel:[0,1,0] op_sel_hi:[1,0,1]"
            : "+v"(ts) : "v"(qx[j]), "v"(pxs));
        asm("v_min3_f32 %0, %0, %1, %2" : "+v"(acc[2*j])   : "v"(td.x), "v"(ts.x));
        asm("v_min3_f32 %0, %0, %1, %2" : "+v"(acc[2*j+1]) : "v"(td.y), "v"(ts.y));
    }
}

// 512 blocks x 512 thr (8 waves). Block = (dir, batch, qgroup of 512
// queries, sweep-quarter seg). Each block stages its 1024-record segment
// (2048 opposite points) into LDS packed, then each wave sweeps 128 records.
__global__ __launch_bounds__(512, 4) void chamfer_kernel(
    const float* __restrict__ xraw, const float* __restrict__ yraw,
    float* __restrict__ partial,        // [NGRP][4 seg][512 q]
    unsigned int* __restrict__ ctrl,    // [NGRP cnt][1 fcnt][1 accum(float)]
    float* __restrict__ out)
{
    __shared__ float4 recs4[2048];      // 32KB: 1024 records x 32B packed
    __shared__ float  red[8 * 512];     // 16KB
    __shared__ unsigned int sflag;

    const int tid  = threadIdx.x;
    const int lane = tid & 63;
    const int wave = __builtin_amdgcn_readfirstlane(tid >> 6);
    const int blk  = blockIdx.x;        // 0..511
    const int dir   = blk >> 8;
    const int batch = (blk >> 6) & 3;
    const int qg    = (blk >> 2) & 15;
    const int seg   = blk & 3;
    const int g     = blk >> 2;         // group 0..127

    const float* qraw = dir ? yraw : xraw;
    const float* oraw = dir ? xraw : yraw;

    // ---- stage: thread packs 2 records (12 raw floats) into LDS ----
    {
        const float4* src4 =
            (const float4*)(oraw + (size_t)(batch * N_ + seg * 2048) * 3) + tid * 3;
        float4 a = src4[0], b = src4[1], c = src4[2];
        // rec0: p0=(a.x,a.y,a.z) p1=(a.w,b.x,b.y); rec1: p0=(b.z,b.w,c.x) p1=(c.y,c.z,c.w)
        float w00 = fmaf(a.x, a.x, fmaf(a.y, a.y, a.z * a.z));
        float w01 = fmaf(a.w, a.w, fmaf(b.x, b.x, b.y * b.y));
        float w10 = fmaf(b.z, b.z, fmaf(b.w, b.w, c.x * c.x));
        float w11 = fmaf(c.y, c.y, fmaf(c.z, c.z, c.w * c.w));
        float4* d = &recs4[tid * 4];
        d[0] = make_float4(a.x, a.w, a.y, b.x);   // {p0x,p1x,p0y,p1y}
        d[1] = make_float4(a.z, b.y, w00, w01);   // {p0z,p1z,w0,w1}
        d[2] = make_float4(b.z, c.y, b.w, c.z);
        d[3] = make_float4(c.x, c.w, w10, w11);
    }

    // ---- load this lane's 8 queries (contiguous 24 floats, 16B-aligned) ----
    const int qbase = batch * N_ + qg * 512;
    float f[24];
    {
        const float4* qv = (const float4*)(qraw + (size_t)qbase * 3) + lane * 6;
        #pragma unroll
        for (int k = 0; k < 6; ++k) {
            float4 t = qv[k];
            f[4*k] = t.x; f[4*k+1] = t.y; f[4*k+2] = t.z; f[4*k+3] = t.w;
        }
    }
    v2f qx[4], qy[4], qz[4];
    float acc[8];
    #pragma unroll
    for (int j = 0; j < 4; ++j) {
        qx[j] = (v2f){-2.0f * f[6*j+0], -2.0f * f[6*j+3]};
        qy[j] = (v2f){-2.0f * f[6*j+1], -2.0f * f[6*j+4]};
        qz[j] = (v2f){-2.0f * f[6*j+2], -2.0f * f[6*j+5]};
        acc[2*j] = FLT_BIG; acc[2*j+1] = FLT_BIG;
    }
    __syncthreads();

    // ---- sweep 128 records via wave-uniform LDS broadcast reads ----
    // wave w owns records [128w, 128w+128) = float4s [256w, 256w+256)
    const float* rp = (const float*)&recs4[wave * 256];
    #pragma unroll 4
    for (int k = 0; k < 128; ++k) {
        v2f pxs = *(const v2f*)(rp + k * 8 + 0);
        v2f pys = *(const v2f*)(rp + k * 8 + 2);
        v2f pzs = *(const v2f*)(rp + k * 8 + 4);
        v2f wv  = *(const v2f*)(rp + k * 8 + 6);
        do_record_v(pxs, pys, pzs, wv, qx, qy, qz, acc);
    }

    // ---- block combine: 8 wave-partials per query ----
    #pragma unroll
    for (int j = 0; j < 8; ++j) red[wave * 512 + lane * 8 + j] = acc[j];
    __syncthreads();
    float m = red[tid];                          // thread t owns query qbase+t
    #pragma unroll
    for (int w = 1; w < 8; ++w) m = fminf(m, red[w * 512 + tid]);

    // ---- per-seg partial min -> ws (plain store, no init needed) ----
    partial[((size_t)g * 4 + seg) * 512 + tid] = m;
    __syncthreads();                             // drains vmcnt: stores in L2
    if (tid == 0) {
        __threadfence();                         // make stores device-visible
        sflag = atomicAdd(&ctrl[g], 1u);
    }
    __syncthreads();
    if (sflag == 3u) {                           // last seg-block: finalize group
        if (tid == 0) __threadfence();           // acquire for fresh reads
        __syncthreads();
        const float* pg = partial + (size_t)g * 4 * 512;
        float mm = fminf(fminf(pg[tid], pg[512 + tid]),
                         fminf(pg[1024 + tid], pg[1536 + tid]));
        int gq = qbase + tid;
        float ax = qraw[gq*3+0], ay = qraw[gq*3+1], az = qraw[gq*3+2];
        float qn = fmaf(ax, ax, fmaf(ay, ay, az * az));
        float d2 = fmaxf(0.0f, qn + mm);         // relu commutes with min
        #pragma unroll
        for (int off = 32; off > 0; off >>= 1) d2 += __shfl_xor(d2, off);
        if (lane == 0) red[wave] = d2;
        __syncthreads();
        if (tid == 0) {
            float s = red[0];
            #pragma unroll
            for (int w = 1; w < 8; ++w) s += red[w];
            atomicAdd((float*)&ctrl[NGRP + 1], s * (1.0f / 32768.0f));
            __threadfence();
            unsigned int o2 = atomicAdd(&ctrl[NGRP], 1u);
            if (o2 == (unsigned)(NGRP - 1)) {    // last group: publish
                float tot = atomicAdd((float*)&ctrl[NGRP + 1], 0.0f);
                *out = tot;
            }
        }
    }
}

// ---------------- fallback (ws too small): round-1 kernel ----------------
__global__ __launch_bounds__(1024) void chamfer_raw_kernel(
    const float* __restrict__ xraw, const float* __restrict__ yraw,
    float* __restrict__ out)
{
    __shared__ float4 red4[16][64];
    const int tid  = threadIdx.x;
    const int wave = tid >> 6;
    const int lane = tid & 63;
    const int blk  = blockIdx.x;
    const bool xdir = (blk < 128);
    const int b    = (blk & 127) >> 5;
    const int qofs = (blk & 31) << 8;
    const float* qraw = xdir ? xraw : yraw;
    const float* oraw = xdir ? yraw : xraw;
    float qx0[4], qx1[4], qx2[4], acc[4];
    #pragma unroll
    for (int q = 0; q < 4; ++q) {
        int gq = b * N_ + qofs + lane*4 + q;
        qx0[q] = qraw[gq*3+0]; qx1[q] = qraw[gq*3+1]; qx2[q] = qraw[gq*3+2];
        acc[q] = FLT_BIG;
    }
    const float* opp = oraw + (size_t)(b * N_ + wave * 512) * 3;
    #pragma unroll 4
    for (int k = 0; k < 512; ++k) {
        float p0 = opp[k*3+0], p1 = opp[k*3+1], p2 = opp[k*3+2];
        float w  = fmaf(p0, p0, fmaf(p1, p1, p2*p2));
        #pragma unroll
        for (int q = 0; q < 4; ++q) {
            float dot = qx0[q]*p0 + qx1[q]*p1 + qx2[q]*p2;
            acc[q] = fminf(acc[q], fmaf(-2.0f, dot, w));
        }
    }
    red4[wave][lane] = make_float4(acc[0], acc[1], acc[2], acc[3]);
    __syncthreads();
    if (tid < 256) {
        const float* red = (const float*)red4;
        float m = red[tid];
        #pragma unroll
        for (int w = 1; w < 16; ++w) m = fminf(m, red[w*256 + tid]);
        int gq = b * N_ + qofs + tid;
        float ax = qraw[gq*3+0], ay = qraw[gq*3+1], az = qraw[gq*3+2];
        float d2 = fmaxf(0.0f, fmaf(ax,ax,fmaf(ay,ay,az*az)) + m);
        #pragma unroll
        for (int off = 32; off > 0; off >>= 1) d2 += __shfl_xor(d2, off);
        if ((tid & 63) == 0) atomicAdd(out, d2 * (1.0f / 32768.0f));
    }
}

extern "C" void kernel_launch(void* const* d_in, const int* in_sizes, int n_in,
                              void* d_out, int out_size, void* d_ws, size_t ws_size,
                              hipStream_t stream)
{
    const float* x = (const float*)d_in[0];
    const float* y = (const float*)d_in[1];
    float* out = (float*)d_out;

    // ws layout: [0,1M) partial mins [128][4][512] f32, then ctrl[130] u32
    const size_t need = (size_t)NGRP * 4 * 512 * sizeof(float) + (NGRP + 2) * 4;
    if (ws_size >= need) {
        float* partial = (float*)d_ws;
        unsigned int* ctrl = (unsigned int*)(partial + (size_t)NGRP * 4 * 512);
        hipMemsetAsync(ctrl, 0, (NGRP + 2) * 4, stream);
        chamfer_kernel<<<512, 512, 0, stream>>>(x, y, partial, ctrl, out);
    } else {
        zero_out_kernel<<<1, 1, 0, stream>>>(out);
        chamfer_raw_kernel<<<256, 1024, 0, stream>>>(x, y, out);
    }
}